// Round 2
// baseline (212.090 us; speedup 1.0000x reference)
//
#include <hip/hip_runtime.h>

#define HW 192
#define DD 512
#define GG 64
#define PP 64
#define SLAB 98304  // 192*512 i8 bytes per slab

typedef __attribute__((ext_vector_type(4))) int intx4;

__device__ __forceinline__ unsigned int pk4(float a, float b, float c, float d) {
  int qa = (int)rintf(a), qb = (int)rintf(b), qc = (int)rintf(c), qd = (int)rintf(d);
  return (unsigned)(qa & 255) | ((unsigned)(qb & 255) << 8) |
         ((unsigned)(qc & 255) << 16) | ((unsigned)(qd & 255) << 24);
}

// L2-normalize over channels -> int8 (q = rint(127*v)), fragment-linear ws:
// ws[slab][kb2(8)][R(12)][lane(64)][16B]
//   pos = R*16 + (lane&15), bytes = channels kb2*64 + (lane>>4)*16 .. +15.
// This is the per-lane operand order of mfma_i32_16x16x64_i8 (16B/lane,
// k = quad*16 + j), so the GEMM stages fragments straight from global
// (1KB contiguous per frag = one global_load_lds_dwordx4 per wave).
__global__ __launch_bounds__(512, 2) void norm_kernel(
    const float* __restrict__ gal, const float* __restrict__ prob,
    unsigned char* __restrict__ ws) {
  int b = blockIdx.x;  // 0..1535
  int s = b / 12;      // slab 0..127
  int q = b - s * 12;  // pos chunk (= R) 0..11
  const float* in = (s < GG) ? (gal + (size_t)s * DD * HW)
                             : (prob + (size_t)(s - GG) * DD * HW);
  unsigned char* out = ws + (size_t)s * SLAB;
  int pos0 = q * 16;
  int t = threadIdx.x;

  __shared__ float T[16][524];   // 33.5 KB, [pos][c]
  __shared__ float sqa[128][17];
  __shared__ float sq2[16][17];
  __shared__ float scl[16];

  {
    int cq = t >> 2;   // 0..127
    int quad = t & 3;  // 0..3
    float p0 = 0.f, p1 = 0.f, p2 = 0.f, p3 = 0.f;
#pragma unroll
    for (int cb = 0; cb < 4; ++cb) {
      int c = cb * 128 + cq;
      const float4 v = *(const float4*)(in + (size_t)c * HW + pos0 + quad * 4);
      T[quad * 4 + 0][c] = v.x;
      T[quad * 4 + 1][c] = v.y;
      T[quad * 4 + 2][c] = v.z;
      T[quad * 4 + 3][c] = v.w;
      p0 += v.x * v.x; p1 += v.y * v.y; p2 += v.z * v.z; p3 += v.w * v.w;
    }
    sqa[cq][quad * 4 + 0] = p0;
    sqa[cq][quad * 4 + 1] = p1;
    sqa[cq][quad * 4 + 2] = p2;
    sqa[cq][quad * 4 + 3] = p3;
  }
  __syncthreads();
  if (t < 256) {
    int g2 = t >> 4, pos = t & 15;
    float v = 0.f;
#pragma unroll
    for (int r = 0; r < 8; ++r) v += sqa[g2 * 8 + r][pos];
    sq2[g2][pos] = v;
  }
  __syncthreads();
  if (t < 16) {
    float v = 0.f;
#pragma unroll
    for (int r = 0; r < 16; ++r) v += sq2[r][t];
    scl[t] = 1.f / fmaxf(sqrtf(v), 1e-12f);
  }
  __syncthreads();

  {
    int kb2 = t >> 6;    // 0..7 (uniform per wave)
    int lane = t & 63;
    int l4 = lane >> 4;  // k-quarter 0..3
    int pos = lane & 15; // 0..15
    float sc = scl[pos] * 127.f;
    int base = kb2 * 64 + l4 * 16;
    const float4 r0 = *(const float4*)&T[pos][base + 0];
    const float4 r1 = *(const float4*)&T[pos][base + 4];
    const float4 r2 = *(const float4*)&T[pos][base + 8];
    const float4 r3 = *(const float4*)&T[pos][base + 12];
    uint4 u;
    u.x = pk4(r0.x * sc, r0.y * sc, r0.z * sc, r0.w * sc);
    u.y = pk4(r1.x * sc, r1.y * sc, r1.z * sc, r1.w * sc);
    u.z = pk4(r2.x * sc, r2.y * sc, r2.z * sc, r2.w * sc);
    u.w = pk4(r3.x * sc, r3.y * sc, r3.z * sc, r3.w * sc);
    *(uint4*)(out + (size_t)kb2 * 12288 + (size_t)q * 1024 + (size_t)lane * 16) = u;
  }
}

// R12: LDS-staged fragments. R0-R11 loaded every fragment twice from L2
// (each A row read by 2 waves, each B col by 2 waves): 1.57 GB / 39.2us
// MFMA-floor = 40 TB/s > 34.5 TB/s L2 ceiling -> structurally L2-bound at
// 40% of MFMA peak (matches MfmaUtil 33%, and matches the null XCD-swizzle
// result: locality wasn't the issue, rate was). Now: per kb2, stage the 24
// unique frags (24KB) ONCE into LDS via global_load_lds_dwordx4 (frag = 1KB
// contiguous = wave-uniform dest + lane*16, exactly the HW constraint),
// double-buffered; waves ds_read_b128 their frags back. L2 demand halves
// (786MB -> 20 TB/s at floor); ds_read (separate pipe, ~85-128 B/cy/CU)
// fits under the 734cy/step MFMA phase. Single barrier per kb2:
//   [vmcnt(0)+bar (implicit in __syncthreads)] [stage next] [ds_read cur]
//   [lgkm][36 MFMA]
// WAR-safe: buf[(k+1)&1] was last read at iter k-1; every wave's barrier
// arrival at iter k implies its lgkmcnt(0) drained, so stage-after-bar
// cannot overwrite an in-flight read. Drained vmcnt at the barrier is an
// L2-hit issued a full MFMA phase earlier -> no m97-style drain stall; the
// co-resident block's MFMAs cover the barrier anyway.
#define GLOAD_LDS16(gp, lp)                                              \
  __builtin_amdgcn_global_load_lds(                                      \
      (const __attribute__((address_space(1))) unsigned int*)(gp),       \
      (__attribute__((address_space(3))) unsigned int*)(lp), 16, 0, 0)

__global__ __launch_bounds__(256, 2) void qaconv_gemm(
    const unsigned char* __restrict__ ws, const float* __restrict__ fcw,
    const float* __restrict__ bnw, const float* __restrict__ bnb,
    const float* __restrict__ bnm, const float* __restrict__ bnv,
    const float* __restrict__ fcb, const float* __restrict__ lw,
    const float* __restrict__ lb, const float* __restrict__ lm,
    const float* __restrict__ lv, float* __restrict__ out) {
  int bid0 = blockIdx.x;
  int bid = ((bid0 & 7) << 9) + (bid0 >> 3);  // XCD-contiguous supertiles
  int sb = bid >> 6, li = bid & 63;           // 8x8 supertiles
  int g = ((sb >> 3) << 3) + (li >> 3);
  int p = ((sb & 7) << 3) + (li & 7);
  const unsigned char* Bsrc = ws + (size_t)g * SLAB;         // galt[g] frags
  const unsigned char* Asrc = ws + (size_t)(GG + p) * SLAB;  // kern[p] frags

  // double-buffered fragment store: buf[b] frag f (0..11 = A R0..11,
  // 12..23 = B R0..11) at f*1024 + lane*16.  2 x 24 KB = 48 KB.
  __shared__ unsigned char sbuf[2][24576];

  int tid = threadIdx.x;
  int lane = tid & 63;
  int wave = tid >> 6;
  int wi = wave >> 1, wj = wave & 1;
  int l15 = lane & 15, l4 = lane >> 4;

  intx4 acc[6][6];
#pragma unroll
  for (int a = 0; a < 6; ++a)
#pragma unroll
    for (int c = 0; c < 6; ++c) acc[a][c] = (intx4){0, 0, 0, 0};

  // staging: wave w owns frags w*6 .. w*6+5  (w<2 -> A rows, w>=2 -> B rows)
  const unsigned char* stgsrc =
      ((wave < 2) ? Asrc : Bsrc) + (size_t)((wave & 1) * 6) * 1024 +
      (size_t)lane * 16;
  int fbase = wave * 6;  // frag index base (uniform per wave)

#define STAGE(BUF, KB)                                                    \
  do {                                                                    \
    const unsigned char* s_ = stgsrc + (size_t)(KB)*12288;                \
    _Pragma("unroll") for (int i_ = 0; i_ < 6; ++i_) {                    \
      GLOAD_LDS16(s_ + i_ * 1024, &sbuf[BUF][(fbase + i_) * 1024]);       \
    }                                                                     \
  } while (0)

  STAGE(0, 0);
#pragma unroll 1
  for (int kb = 0; kb < 8; ++kb) {
    __syncthreads();  // implicit vmcnt(0): buf[kb&1] fully staged, all waves
    if (kb < 7) STAGE((kb + 1) & 1, kb + 1);
    const unsigned char* cb = &sbuf[kb & 1][lane * 16];
    intx4 a[6], b[6];
#pragma unroll
    for (int i = 0; i < 6; ++i) {
      a[i] = *(const intx4*)(cb + (wi * 6 + i) * 1024);
      b[i] = *(const intx4*)(cb + (12 + wj * 6 + i) * 1024);
    }
#pragma unroll
    for (int jt = 0; jt < 6; ++jt) {
      intx4 bb = b[jt];
#pragma unroll
      for (int it = 0; it < 6; ++it)
        acc[it][jt] = __builtin_amdgcn_mfma_i32_16x16x64_i8(a[it], bb,
                                                            acc[it][jt], 0, 0, 0);
    }
  }
#undef STAGE

  __syncthreads();  // all ds_reads done; safe to reuse sbuf for epilogue

  // epilogue scratch aliases the stage buffer (saves LDS)
  float (*colpart)[HW] = (float (*)[HW]) & sbuf[0][0];      // [2][192]
  float (*rowpart)[HW] = (float (*)[HW]) & sbuf[0][1536];   // [2][192]
  float (*redbuf)[2] = (float (*)[2]) & sbuf[0][3072];      // [4][2]

  // ---- epilogue: dual max-pool in int32 ----
  // C/D layout: i = wi*96 + it*16 + l4*4 + r ; j = wj*96 + jt*16 + l15
  const float inv = 1.f / 16129.f;  // 1/127^2
  int cm[6];
  int rm[6][4];
#pragma unroll
  for (int jt = 0; jt < 6; ++jt) cm[jt] = -2147483647;
#pragma unroll
  for (int it = 0; it < 6; ++it)
#pragma unroll
    for (int r = 0; r < 4; ++r) rm[it][r] = -2147483647;
#pragma unroll
  for (int it = 0; it < 6; ++it)
#pragma unroll
    for (int jt = 0; jt < 6; ++jt)
#pragma unroll
      for (int r = 0; r < 4; ++r) {
        int v = acc[it][jt][r];
        cm[jt] = max(cm[jt], v);
        rm[it][r] = max(rm[it][r], v);
      }

#pragma unroll
  for (int jt = 0; jt < 6; ++jt) {
    int v = cm[jt];
    v = max(v, __shfl_xor(v, 16, 64));
    v = max(v, __shfl_xor(v, 32, 64));
    if (lane < 16) colpart[wi][wj * 96 + jt * 16 + lane] = (float)v * inv;
  }
#pragma unroll
  for (int it = 0; it < 6; ++it)
#pragma unroll
    for (int r = 0; r < 4; ++r) {
      int v = rm[it][r];
      v = max(v, __shfl_xor(v, 1, 64));
      v = max(v, __shfl_xor(v, 2, 64));
      v = max(v, __shfl_xor(v, 4, 64));
      v = max(v, __shfl_xor(v, 8, 64));
      if (l15 == 0) rowpart[wj][wi * 96 + it * 16 + l4 * 4 + r] = (float)v * inv;
    }
  __syncthreads();

  // ---- fused BN -> fc -> lbn -> sigmoid ----
  float part = 0.f, wpart = 0.f;
  if (tid < HW) {
    float cmax = fmaxf(colpart[0][tid], colpart[1][tid]);  // score[j]
    float rmax = fmaxf(rowpart[0][tid], rowpart[1][tid]);  // score[192+i]
    float w1 = fcw[tid], w2 = fcw[HW + tid];
    part = cmax * w1 + rmax * w2;
    wpart = w1 + w2;
  }
#pragma unroll
  for (int off = 32; off > 0; off >>= 1) {
    part += __shfl_down(part, off, 64);
    wpart += __shfl_down(wpart, off, 64);
  }
  if (lane == 0) { redbuf[wave][0] = part; redbuf[wave][1] = wpart; }
  __syncthreads();
  if (tid == 0) {
    float s = redbuf[0][0] + redbuf[1][0] + redbuf[2][0] + redbuf[3][0];
    float wsum = redbuf[0][1] + redbuf[1][1] + redbuf[2][1] + redbuf[3][1];
    float bnA = bnw[0] * rsqrtf(bnv[0] + 1e-5f);
    float bnB = bnb[0] - bnm[0] * bnA;
    float sc = bnA * s + bnB * wsum + fcb[0];
    float lA = lw[0] * rsqrtf(lv[0] + 1e-5f);
    sc = (sc - lm[0]) * lA + lb[0];
    out[g * PP + p] = 1.f / (1.f + __expf(-sc * 0.1f));
  }
}

extern "C" void kernel_launch(void* const* d_in, const int* in_sizes, int n_in,
                              void* d_out, int out_size, void* d_ws, size_t ws_size,
                              hipStream_t stream) {
  const float* gal  = (const float*)d_in[0];
  const float* prob = (const float*)d_in[1];
  const float* bnw  = (const float*)d_in[2];
  const float* bnb  = (const float*)d_in[3];
  const float* bnm  = (const float*)d_in[4];
  const float* bnv  = (const float*)d_in[5];
  const float* fcw  = (const float*)d_in[6];
  const float* fcb  = (const float*)d_in[7];
  const float* lw   = (const float*)d_in[8];
  const float* lb   = (const float*)d_in[9];
  const float* lm   = (const float*)d_in[10];
  const float* lv   = (const float*)d_in[11];
  unsigned char* ws = (unsigned char*)d_ws;
  float* out = (float*)d_out;

  hipLaunchKernelGGL(norm_kernel, dim3(1536), dim3(512), 0, stream, gal, prob, ws);
  hipLaunchKernelGGL(qaconv_gemm, dim3(GG * PP), dim3(256), 0, stream, ws, fcw,
                     bnw, bnb, bnm, bnv, fcb, lw, lb, lm, lv, out);
}

// Round 3
// 205.776 us; speedup vs baseline: 1.0307x; 1.0307x over previous
//
#include <hip/hip_runtime.h>

#define HW 192
#define DD 512
#define GG 64
#define PP 64
#define SLAB 98304  // 192*512 i8 bytes per slab

typedef __attribute__((ext_vector_type(4))) int intx4;

__device__ __forceinline__ unsigned int pk4(float a, float b, float c, float d) {
  int qa = (int)rintf(a), qb = (int)rintf(b), qc = (int)rintf(c), qd = (int)rintf(d);
  return (unsigned)(qa & 255) | ((unsigned)(qb & 255) << 8) |
         ((unsigned)(qc & 255) << 16) | ((unsigned)(qd & 255) << 24);
}

// L2-normalize over channels -> int8 (q = rint(127*v)), fragment-linear ws:
// ws[slab][kb2(8)][R(12)][lane(64)][16B]
//   pos = R*16 + (lane&15), bytes = channels kb2*64 + (lane>>4)*16 .. +15.
// This is the per-lane operand order of mfma_i32_16x16x64_i8 (16B/lane,
// k = quad*16 + j), so the GEMM stages fragments straight from global
// (1KB contiguous per frag = one global_load_lds_dwordx4 per wave).
__global__ __launch_bounds__(512, 2) void norm_kernel(
    const float* __restrict__ gal, const float* __restrict__ prob,
    unsigned char* __restrict__ ws) {
  int b = blockIdx.x;  // 0..1535
  int s = b / 12;      // slab 0..127
  int q = b - s * 12;  // pos chunk (= R) 0..11
  const float* in = (s < GG) ? (gal + (size_t)s * DD * HW)
                             : (prob + (size_t)(s - GG) * DD * HW);
  unsigned char* out = ws + (size_t)s * SLAB;
  int pos0 = q * 16;
  int t = threadIdx.x;

  __shared__ float T[16][524];   // 33.5 KB, [pos][c]
  __shared__ float sqa[128][17];
  __shared__ float sq2[16][17];
  __shared__ float scl[16];

  {
    int cq = t >> 2;   // 0..127
    int quad = t & 3;  // 0..3
    float p0 = 0.f, p1 = 0.f, p2 = 0.f, p3 = 0.f;
#pragma unroll
    for (int cb = 0; cb < 4; ++cb) {
      int c = cb * 128 + cq;
      const float4 v = *(const float4*)(in + (size_t)c * HW + pos0 + quad * 4);
      T[quad * 4 + 0][c] = v.x;
      T[quad * 4 + 1][c] = v.y;
      T[quad * 4 + 2][c] = v.z;
      T[quad * 4 + 3][c] = v.w;
      p0 += v.x * v.x; p1 += v.y * v.y; p2 += v.z * v.z; p3 += v.w * v.w;
    }
    sqa[cq][quad * 4 + 0] = p0;
    sqa[cq][quad * 4 + 1] = p1;
    sqa[cq][quad * 4 + 2] = p2;
    sqa[cq][quad * 4 + 3] = p3;
  }
  __syncthreads();
  if (t < 256) {
    int g2 = t >> 4, pos = t & 15;
    float v = 0.f;
#pragma unroll
    for (int r = 0; r < 8; ++r) v += sqa[g2 * 8 + r][pos];
    sq2[g2][pos] = v;
  }
  __syncthreads();
  if (t < 16) {
    float v = 0.f;
#pragma unroll
    for (int r = 0; r < 16; ++r) v += sq2[r][t];
    scl[t] = 1.f / fmaxf(sqrtf(v), 1e-12f);
  }
  __syncthreads();

  {
    int kb2 = t >> 6;    // 0..7 (uniform per wave)
    int lane = t & 63;
    int l4 = lane >> 4;  // k-quarter 0..3
    int pos = lane & 15; // 0..15
    float sc = scl[pos] * 127.f;
    int base = kb2 * 64 + l4 * 16;
    const float4 r0 = *(const float4*)&T[pos][base + 0];
    const float4 r1 = *(const float4*)&T[pos][base + 4];
    const float4 r2 = *(const float4*)&T[pos][base + 8];
    const float4 r3 = *(const float4*)&T[pos][base + 12];
    uint4 u;
    u.x = pk4(r0.x * sc, r0.y * sc, r0.z * sc, r0.w * sc);
    u.y = pk4(r1.x * sc, r1.y * sc, r1.z * sc, r1.w * sc);
    u.z = pk4(r2.x * sc, r2.y * sc, r2.z * sc, r2.w * sc);
    u.w = pk4(r3.x * sc, r3.y * sc, r3.z * sc, r3.w * sc);
    *(uint4*)(out + (size_t)kb2 * 12288 + (size_t)q * 1024 + (size_t)lane * 16) = u;
  }
}

// R13: LDS dedup + REGISTER double-buffer (3-stage pipeline).
// Diagnosis: R11 (direct loads) is global-path-delivery-bound: 96 KB/CU per
// kb2-round (2x intra-block duplication) at ~64 B/cy/CU = ~1536cy > 1469cy
// of MFMA work -> 16 rounds x 1536cy = ~98us (matches). R12's staging fixed
// the traffic (48 KB/CU/round) but serialized: MFMAs depended on same-iter
// ds_reads, so every barrier was followed by ~1000cy of DS-pipe drain before
// any MFMA (-> 115us). Fix: 3-stage schedule per iter kb:
//   barrier -> STAGE(kb+2 -> buf[kb&1]) -> ds_read(kb+1 -> regs[(kb+1)&1])
//           -> MFMA(regs[kb&1])   [no wait: loaded LAST iter]
// Per-iter barrier drains are free (ops issued a full ~1500cy earlier).
// WAR-safe: STAGE(kb+2) overwrites buf[kb&1]; every wave's ds_read of tile
// kb finished before it arrived at this barrier. Loop fully unrolled so
// buffer indices are compile-time (no scratch, rule #20).
// Budget/round/CU: global 48KB=768cy, DS 96KB=768-1100cy (separate pipe,
// overlapped), MFMA 1469cy -> MFMA-bound, predict ~50-62us.
#define GLOAD_LDS16(gp, lp)                                              \
  __builtin_amdgcn_global_load_lds(                                      \
      (const __attribute__((address_space(1))) unsigned int*)(gp),       \
      (__attribute__((address_space(3))) unsigned int*)(lp), 16, 0, 0)

__global__ __launch_bounds__(256, 2) void qaconv_gemm(
    const unsigned char* __restrict__ ws, const float* __restrict__ fcw,
    const float* __restrict__ bnw, const float* __restrict__ bnb,
    const float* __restrict__ bnm, const float* __restrict__ bnv,
    const float* __restrict__ fcb, const float* __restrict__ lw,
    const float* __restrict__ lb, const float* __restrict__ lm,
    const float* __restrict__ lv, float* __restrict__ out) {
  int bid0 = blockIdx.x;
  int bid = ((bid0 & 7) << 9) + (bid0 >> 3);  // XCD-contiguous supertiles
  int sb = bid >> 6, li = bid & 63;           // 8x8 supertiles
  int g = ((sb >> 3) << 3) + (li >> 3);
  int p = ((sb & 7) << 3) + (li & 7);
  const unsigned char* Bsrc = ws + (size_t)g * SLAB;         // galt[g] frags
  const unsigned char* Asrc = ws + (size_t)(GG + p) * SLAB;  // kern[p] frags

  // double-buffered fragment store: buf[b] frag f (0..11 = A R0..11,
  // 12..23 = B R0..11) at f*1024 + lane*16.  2 x 24 KB = 48 KB.
  __shared__ unsigned char sbuf[2][24576];

  int tid = threadIdx.x;
  int lane = tid & 63;
  int wave = tid >> 6;
  int wi = wave >> 1, wj = wave & 1;
  int l15 = lane & 15, l4 = lane >> 4;

  intx4 acc[6][6];
#pragma unroll
  for (int a = 0; a < 6; ++a)
#pragma unroll
    for (int c = 0; c < 6; ++c) acc[a][c] = (intx4){0, 0, 0, 0};

  // staging: wave w owns frags w*6 .. w*6+5  (w<2 -> A rows, w>=2 -> B rows)
  const unsigned char* stgsrc =
      ((wave < 2) ? Asrc : Bsrc) + (size_t)((wave & 1) * 6) * 1024 +
      (size_t)lane * 16;
  int fbase = wave * 6;  // frag index base (uniform per wave)

#define STAGE(BUF, KB)                                                    \
  do {                                                                    \
    const unsigned char* s_ = stgsrc + (size_t)(KB)*12288;                \
    _Pragma("unroll") for (int i_ = 0; i_ < 6; ++i_) {                    \
      GLOAD_LDS16(s_ + i_ * 1024, &sbuf[BUF][(fbase + i_) * 1024]);       \
    }                                                                     \
  } while (0)

  // register double-buffer: rb = tile kb & 1
  intx4 aR[2][6], bR[2][6];

#define DSRD(RB, KB)                                                      \
  do {                                                                    \
    const unsigned char* cb_ = &sbuf[(KB)&1][lane * 16];                  \
    _Pragma("unroll") for (int i_ = 0; i_ < 6; ++i_) {                    \
      aR[RB][i_] = *(const intx4*)(cb_ + (wi * 6 + i_) * 1024);           \
      bR[RB][i_] = *(const intx4*)(cb_ + (12 + wj * 6 + i_) * 1024);      \
    }                                                                     \
  } while (0)

  STAGE(0, 0);
  __syncthreads();  // vmcnt(0): buf0 staged
  DSRD(0, 0);
  STAGE(1, 1);

#pragma unroll
  for (int kb = 0; kb < 8; ++kb) {
    // Drains (all ~1500cy old -> free): my ds_read(kb) [feeds this iter's
    // MFMA], stage(kb+1) vmcnt [feeds this iter's DSRD], and proves all
    // waves consumed tile kb's LDS copy [WAR for STAGE below].
    __syncthreads();
    if (kb < 6) STAGE(kb & 1, kb + 2);
    if (kb < 7) DSRD((kb + 1) & 1, kb + 1);
#pragma unroll
    for (int jt = 0; jt < 6; ++jt) {
      intx4 bb = bR[kb & 1][jt];
#pragma unroll
      for (int it = 0; it < 6; ++it)
        acc[it][jt] = __builtin_amdgcn_mfma_i32_16x16x64_i8(
            aR[kb & 1][it], bb, acc[it][jt], 0, 0, 0);
    }
  }
#undef STAGE
#undef DSRD

  __syncthreads();  // all ds_reads done; safe to reuse sbuf for epilogue

  // epilogue scratch aliases the stage buffer (saves LDS)
  float (*colpart)[HW] = (float (*)[HW]) & sbuf[0][0];      // [2][192]
  float (*rowpart)[HW] = (float (*)[HW]) & sbuf[0][1536];   // [2][192]
  float (*redbuf)[2] = (float (*)[2]) & sbuf[0][3072];      // [4][2]

  // ---- epilogue: dual max-pool in int32 ----
  // C/D layout: i = wi*96 + it*16 + l4*4 + r ; j = wj*96 + jt*16 + l15
  const float inv = 1.f / 16129.f;  // 1/127^2
  int cm[6];
  int rm[6][4];
#pragma unroll
  for (int jt = 0; jt < 6; ++jt) cm[jt] = -2147483647;
#pragma unroll
  for (int it = 0; it < 6; ++it)
#pragma unroll
    for (int r = 0; r < 4; ++r) rm[it][r] = -2147483647;
#pragma unroll
  for (int it = 0; it < 6; ++it)
#pragma unroll
    for (int jt = 0; jt < 6; ++jt)
#pragma unroll
      for (int r = 0; r < 4; ++r) {
        int v = acc[it][jt][r];
        cm[jt] = max(cm[jt], v);
        rm[it][r] = max(rm[it][r], v);
      }

#pragma unroll
  for (int jt = 0; jt < 6; ++jt) {
    int v = cm[jt];
    v = max(v, __shfl_xor(v, 16, 64));
    v = max(v, __shfl_xor(v, 32, 64));
    if (lane < 16) colpart[wi][wj * 96 + jt * 16 + lane] = (float)v * inv;
  }
#pragma unroll
  for (int it = 0; it < 6; ++it)
#pragma unroll
    for (int r = 0; r < 4; ++r) {
      int v = rm[it][r];
      v = max(v, __shfl_xor(v, 1, 64));
      v = max(v, __shfl_xor(v, 2, 64));
      v = max(v, __shfl_xor(v, 4, 64));
      v = max(v, __shfl_xor(v, 8, 64));
      if (l15 == 0) rowpart[wj][wi * 96 + it * 16 + l4 * 4 + r] = (float)v * inv;
    }
  __syncthreads();

  // ---- fused BN -> fc -> lbn -> sigmoid ----
  float part = 0.f, wpart = 0.f;
  if (tid < HW) {
    float cmax = fmaxf(colpart[0][tid], colpart[1][tid]);  // score[j]
    float rmax = fmaxf(rowpart[0][tid], rowpart[1][tid]);  // score[192+i]
    float w1 = fcw[tid], w2 = fcw[HW + tid];
    part = cmax * w1 + rmax * w2;
    wpart = w1 + w2;
  }
#pragma unroll
  for (int off = 32; off > 0; off >>= 1) {
    part += __shfl_down(part, off, 64);
    wpart += __shfl_down(wpart, off, 64);
  }
  if (lane == 0) { redbuf[wave][0] = part; redbuf[wave][1] = wpart; }
  __syncthreads();
  if (tid == 0) {
    float s = redbuf[0][0] + redbuf[1][0] + redbuf[2][0] + redbuf[3][0];
    float wsum = redbuf[0][1] + redbuf[1][1] + redbuf[2][1] + redbuf[3][1];
    float bnA = bnw[0] * rsqrtf(bnv[0] + 1e-5f);
    float bnB = bnb[0] - bnm[0] * bnA;
    float sc = bnA * s + bnB * wsum + fcb[0];
    float lA = lw[0] * rsqrtf(lv[0] + 1e-5f);
    sc = (sc - lm[0]) * lA + lb[0];
    out[g * PP + p] = 1.f / (1.f + __expf(-sc * 0.1f));
  }
}

extern "C" void kernel_launch(void* const* d_in, const int* in_sizes, int n_in,
                              void* d_out, int out_size, void* d_ws, size_t ws_size,
                              hipStream_t stream) {
  const float* gal  = (const float*)d_in[0];
  const float* prob = (const float*)d_in[1];
  const float* bnw  = (const float*)d_in[2];
  const float* bnb  = (const float*)d_in[3];
  const float* bnm  = (const float*)d_in[4];
  const float* bnv  = (const float*)d_in[5];
  const float* fcw  = (const float*)d_in[6];
  const float* fcb  = (const float*)d_in[7];
  const float* lw   = (const float*)d_in[8];
  const float* lb   = (const float*)d_in[9];
  const float* lm   = (const float*)d_in[10];
  const float* lv   = (const float*)d_in[11];
  unsigned char* ws = (unsigned char*)d_ws;
  float* out = (float*)d_out;

  hipLaunchKernelGGL(norm_kernel, dim3(1536), dim3(512), 0, stream, gal, prob, ws);
  hipLaunchKernelGGL(qaconv_gemm, dim3(GG * PP), dim3(256), 0, stream, ws, fcw,
                     bnw, bnb, bnm, bnv, fcb, lw, lb, lm, lv, out);
}